// Round 14
// baseline (329.616 us; speedup 1.0000x reference)
//
#include <hip/hip_runtime.h>

#define DIM 1024
#define SEQ 4096
#define MROWS 16384      // BATCH * SEQ
#define CHUNK 64
#define NCHUNKBLKS 256   // MROWS / CHUNK

typedef float  f32x4  __attribute__((ext_vector_type(4)));
typedef __bf16 bf16x8 __attribute__((ext_vector_type(8)));
typedef __bf16 bf16x4 __attribute__((ext_vector_type(4)));

// async global->LDS, 16B per lane. LDS dest is wave-uniform base + lane*16.
__device__ __forceinline__ void gld16(const void* g, void* l) {
  __builtin_amdgcn_global_load_lds((__attribute__((address_space(1))) void*)g,
                                   (__attribute__((address_space(3))) void*)l,
                                   16, 0, 0);
}

__device__ __forceinline__ f32x4 ld4f(const __bf16* p) {
  bf16x4 v = *(const bf16x4*)p;
  f32x4 r;
#pragma unroll
  for (int j = 0; j < 4; ++j) r[j] = (float)v[j];
  return r;
}

// BK=64 K-loop, single-buffer (proven best structure on this problem: five
// deeper-pipeline/structural variants all regressed). T2 both-sides XOR
// swizzle -> 0 bank conflicts (verified).
#define KLOOP64(As_, Bs_, Ag_, Bg_, AsL_, BsL_)                                  \
  for (int kt = 0; kt < DIM / 64; ++kt) {                                        \
    const __bf16* a_ = Ag_ + kt * 64;                                            \
    const __bf16* b_ = Bg_ + kt * 64;                                            \
    _Pragma("unroll") for (int i = 0; i < 4; ++i) {                              \
      gld16(a_ + i * 32 * DIM, AsL_ + i * 4096);                                 \
      gld16(b_ + i * 32 * DIM, BsL_ + i * 4096);                                 \
    }                                                                            \
    __syncthreads();                                                             \
    const bf16x8* Av_ = (const bf16x8*)(As_);                                    \
    const bf16x8* Bv_ = (const bf16x8*)(Bs_);                                    \
    _Pragma("unroll") for (int kk = 0; kk < 2; ++kk) {                           \
      bf16x8 af[4], bfv[4];                                                      \
      const int pc = (kk * 4 + kg) ^ (lane & 7);                                 \
      _Pragma("unroll") for (int i = 0; i < 4; ++i) af[i]  = Av_[(ar + i*16)*8 + pc]; \
      _Pragma("unroll") for (int i = 0; i < 4; ++i) bfv[i] = Bv_[(br + i*16)*8 + pc]; \
      _Pragma("unroll") for (int mi = 0; mi < 4; ++mi)                           \
        _Pragma("unroll") for (int ni = 0; ni < 4; ++ni)                         \
          acc[mi][ni] = __builtin_amdgcn_mfma_f32_16x16x32_bf16(af[mi], bfv[ni], acc[mi][ni], 0, 0, 0); \
    }                                                                            \
    __syncthreads();                                                             \
  }

// Common per-thread geometry (4 waves, 128x128 tile, BK=64, 128B LDS rows).
#define GEMM_PROLOG64(A_, B_)                                                    \
  const int tid  = threadIdx.x;                                                  \
  const int lane = tid & 63;                                                     \
  const int widx = tid >> 6;                                                     \
  const int wr   = widx >> 1, wc = widx & 1;                                     \
  const int kc = ((lane & 7) ^ ((lane >> 3) & 7)) * 8;                           \
  const __bf16* Ag = (A_) + (size_t)(row0 + widx * 8 + (lane >> 3)) * DIM + kc;  \
  const __bf16* Bg = (B_) + (size_t)(col0 + widx * 8 + (lane >> 3)) * DIM + kc;  \
  char* AsL = (char*)As + widx * 1024;                                           \
  char* BsL = (char*)Bs + widx * 1024;                                           \
  f32x4 acc[4][4] = {};                                                          \
  const int ar = wr * 64 + (lane & 15);                                          \
  const int br = wc * 64 + (lane & 15);                                          \
  const int kg = lane >> 4;

// Final residual GEMM: out f32 = acc + bias + (float)xres_bf16.
// XCD row-band remap, grid (8,128).
__global__ __launch_bounds__(256, 2)
void gemm_fin(const __bf16* __restrict__ A, const __bf16* __restrict__ Bt,
              const float* __restrict__ bias, float* __restrict__ of,
              const __bf16* __restrict__ xres)
{
  __shared__ __bf16 As[128 * 64];   // 16 KB
  __shared__ __bf16 Bs[128 * 64];
  const int b = blockIdx.y * 8 + blockIdx.x;   // grid (8,128)
  const int xcd = b & 7, slot = b >> 3;
  const int col_t = slot & 7;
  const int row_t = (xcd << 4) | (slot >> 3);
  const int row0 = row_t * 128, col0 = col_t * 128;

  GEMM_PROLOG64(A, Bt)
  KLOOP64(As, Bs, Ag, Bg, AsL, BsL)

  // C/D frag mapping (HW-verified): col = lane&15, row = (lane>>4)*4 + r
  const int ccol = col0 + wc * 64 + (lane & 15);
  const int crow = row0 + wr * 64 + kg * 4;
  float bvv[4];
#pragma unroll
  for (int ni = 0; ni < 4; ++ni) bvv[ni] = bias[ccol + ni * 16];
#pragma unroll
  for (int mi = 0; mi < 4; ++mi)
#pragma unroll
    for (int ni = 0; ni < 4; ++ni)
#pragma unroll
      for (int r = 0; r < 4; ++r) {
        const int row = crow + mi * 16 + r;
        const size_t idx = (size_t)row * DIM + ccol + ni * 16;
        of[idx] = acc[mi][ni][r] + bvv[ni] + (float)xres[idx];
      }
}

// Weight-combine GEMM (1024^3 x2): out bf16 = acc * ms.
__global__ __launch_bounds__(256, 2)
void gemm_wc(const __bf16* __restrict__ A, const __bf16* __restrict__ Bt,
             void* __restrict__ outp, const float* __restrict__ mscp,
             const __bf16* __restrict__ A2, const __bf16* __restrict__ Bt2,
             void* __restrict__ out2)
{
  __shared__ __bf16 As[128 * 64];
  __shared__ __bf16 Bs[128 * 64];
  if (blockIdx.z == 1) { A = A2; Bt = Bt2; outp = out2; }
  const int row0 = blockIdx.y * 128, col0 = blockIdx.x * 128;

  GEMM_PROLOG64(A, Bt)
  KLOOP64(As, Bs, Ag, Bg, AsL, BsL)

  const int ccol = col0 + wc * 64 + (lane & 15);
  const int crow = row0 + wr * 64 + kg * 4;
  const float ms = mscp[0];
#pragma unroll
  for (int mi = 0; mi < 4; ++mi)
#pragma unroll
    for (int ni = 0; ni < 4; ++ni)
#pragma unroll
      for (int r = 0; r < 4; ++r) {
        const int row = crow + mi * 16 + r;
        const int col = ccol + ni * 16;
        ((__bf16*)outp)[(size_t)row * DIM + col] = (__bf16)(acc[mi][ni][r] * ms);
      }
}

// Fused x-GEMM (PROVEN 103.5 us structure): C[16384,3072] = xb @ Ball^T,
// Ball rows = [WvT | WkmP | WqmP]. out = bf16(acc + bias); base add + wrap
// deferred to phasor. Grid (24,128). XCD band swizzle, ROW-fastest within XCD.
__global__ __launch_bounds__(256, 2)
void gemm3(const __bf16* __restrict__ A, const __bf16* __restrict__ Ball,
           const float* __restrict__ biasAll,
           __bf16* __restrict__ valb, __bf16* __restrict__ kphb,
           __bf16* __restrict__ qphb)
{
  __shared__ __bf16 As[128 * 64];
  __shared__ __bf16 Bs[128 * 64];
  const int b = blockIdx.y * 24 + blockIdx.x;   // linear id, grid (24,128)
  const int xcd = b & 7, p = b >> 3;            // p in [0,384), bijective
  const int col_t = p / 16;                     // col changes slowest
  const int row_t = (xcd << 4) + (p & 15);      // row-fastest within XCD band
  const int row0 = row_t * 128, col0 = col_t * 128;

  GEMM_PROLOG64(A, Ball)
  KLOOP64(As, Bs, Ag, Bg, AsL, BsL)

  const int band = col_t >> 3;                  // 0:V 1:kph 2:qph
  const int ccol = col0 + wc * 64 + (lane & 15);
  const int lcol0 = ccol & 1023;                // col within the 1024-band
  const int crow = row0 + wr * 64 + kg * 4;
  float bvv[4];
#pragma unroll
  for (int ni = 0; ni < 4; ++ni) bvv[ni] = biasAll[ccol + ni * 16];
  __bf16* outb = (band == 0) ? valb : (band == 1) ? kphb : qphb;
#pragma unroll
  for (int mi = 0; mi < 4; ++mi)
#pragma unroll
    for (int ni = 0; ni < 4; ++ni)
#pragma unroll
      for (int r = 0; r < 4; ++r) {
        const int row = crow + mi * 16 + r;
        const size_t idx = (size_t)row * DIM + lcol0 + ni * 16;
        outb[idx] = (__bf16)(acc[mi][ni][r] + bvv[ni]);
      }
}

// Per chunk (64 rows) x full D: phase = baseb[row&4095] + mod (both bf16);
// in-register cumsum of value*e^{i*kph}, retrieve with qph, /sqrt(D),
// per-row LayerNorm, emit bf16 normed. 8-row batches for shfl-chain ILP.
// (Round-11 proven version: 256 thr, 4 cols/thread, 8B/lane loads — the
// 512-thr/2-col variant regressed on load width.)
// nb ALIASES kph (nbuf = kphb): batch reads complete before writes to those
// rows; kph/nb deliberately NOT __restrict__.
__global__ __launch_bounds__(256)
void phasor_ln(const __bf16* __restrict__ val, const __bf16* kph,
               const __bf16* __restrict__ qph, const __bf16* __restrict__ baseb,
               const float* __restrict__ g, const float* __restrict__ lb,
               __bf16* nb)
{
  const int t = threadIdx.x;
  const int w = t >> 6, lane = t & 63;
  const size_t r0 = (size_t)blockIdx.x * CHUNK;
  const int c = t * 4;
  const f32x4 gv  = ((const f32x4*)g)[t];
  const f32x4 lbv = ((const f32x4*)lb)[t];
  __shared__ float redS[8][4], redQ[8][4];
  float mr[4] = {0.f, 0.f, 0.f, 0.f};
  float mi[4] = {0.f, 0.f, 0.f, 0.f};
  for (int rb = 0; rb < 8; ++rb) {
    float ret[8][4], ss[8], qq[8];
#pragma unroll
    for (int r = 0; r < 8; ++r) {
      const int row = rb * 8 + r;
      const size_t base = (r0 + row) * DIM + c;
      const f32x4 v  = ld4f(val + base);
      const f32x4 kp = ld4f(kph + base);
      const f32x4 qp = ld4f(qph + base);
      const f32x4 bp = ld4f(baseb + (size_t)((r0 + row) & (SEQ - 1)) * DIM + c);
      float s = 0.f, q = 0.f;
#pragma unroll
      for (int j = 0; j < 4; ++j) {
        float sk, ck, sq, cq;
        __sincosf(bp[j] + kp[j], &sk, &ck);
        mr[j] += v[j] * ck;
        mi[j] += v[j] * sk;
        __sincosf(bp[j] + qp[j], &sq, &cq);
        ret[r][j] = (mr[j] * cq + mi[j] * sq) * 0.03125f;   // 1/sqrt(1024)
        s += ret[r][j];
        q += ret[r][j] * ret[r][j];
      }
      ss[r] = s; qq[r] = q;
    }
#pragma unroll
    for (int off = 32; off > 0; off >>= 1)
#pragma unroll
      for (int r = 0; r < 8; ++r) {
        ss[r] += __shfl_down(ss[r], off);
        qq[r] += __shfl_down(qq[r], off);
      }
    if (lane == 0)
#pragma unroll
      for (int r = 0; r < 8; ++r) { redS[r][w] = ss[r]; redQ[r][w] = qq[r]; }
    __syncthreads();
#pragma unroll
    for (int r = 0; r < 8; ++r) {
      const float mu   = (redS[r][0] + redS[r][1] + redS[r][2] + redS[r][3]) * (1.0f / DIM);
      const float varr = (redQ[r][0] + redQ[r][1] + redQ[r][2] + redQ[r][3]) * (1.0f / DIM) - mu * mu;
      const float rinv = rsqrtf(varr + 1e-5f);
      bf16x4 o;
#pragma unroll
      for (int j = 0; j < 4; ++j) o[j] = (__bf16)((ret[r][j] - mu) * rinv * gv[j] + lbv[j]);
      *(bf16x4*)(nb + (r0 + rb * 8 + r) * DIM + c) = o;
    }
    __syncthreads();
  }
}

// ---------------------------------------------------------------------------
// ONE merged prep dispatch (block-segmented):
//  seg0: f2b x->xb                       (16384 blocks)
//  seg1: wrap+bf16 basep->baseb          ( 4096 blocks)
//  seg2: biasAll[0:1024) = bv            (    1 block )
//  seg3: 6 weight transposes/converts    ( 6144 blocks)
//  seg4: full-K bias combine (2 blocks, no atomics: sole writer of [1024,3072))
// Segments are independent (disjoint outputs) -> no intra-kernel ordering needed.
// ---------------------------------------------------------------------------
#define NB0 16384
#define NB1 4096
#define NB2 1
#define NB3 6144
__global__ void prep_all(const float* __restrict__ x, __bf16* __restrict__ xb,
                         const float* __restrict__ basep, __bf16* __restrict__ baseb,
                         const float* __restrict__ bv, const float* __restrict__ ms,
                         float* __restrict__ biasAll,
                         const float* __restrict__ Wv, __bf16* __restrict__ d0,
                         const float* __restrict__ Wo, __bf16* __restrict__ d1,
                         const float* __restrict__ Wkm, __bf16* __restrict__ d2,
                         const float* __restrict__ Wqm, __bf16* __restrict__ d3,
                         const float* __restrict__ Wk, __bf16* __restrict__ d4,
                         const float* __restrict__ Wq, __bf16* __restrict__ d5,
                         const float* __restrict__ bk, const float* __restrict__ bkm,
                         const float* __restrict__ bq, const float* __restrict__ bqm)
{
  __shared__ float tle[32][33];
  const int blk = blockIdx.x;
  const int t = threadIdx.x;
  if (blk < NB0) {
    const int i = blk * 256 + t;
    f32x4 vv = ((const f32x4*)x)[i];
    bf16x4 o;
#pragma unroll
    for (int j = 0; j < 4; ++j) o[j] = (__bf16)vv[j];
    ((bf16x4*)xb)[i] = o;
  } else if (blk < NB0 + NB1) {
    const int i = (blk - NB0) * 256 + t;
    f32x4 vv = ((const f32x4*)basep)[i];
    bf16x4 o;
#pragma unroll
    for (int j = 0; j < 4; ++j) {
      float v = vv[j];
      v -= 6.2831853f * rintf(v * 0.15915494f);
      o[j] = (__bf16)v;
    }
    ((bf16x4*)baseb)[i] = o;
  } else if (blk < NB0 + NB1 + NB2) {
    // 1 block, 256 threads x 4: biasAll[0:1024) = bv
    const int n = t * 4;
    *(f32x4*)(biasAll + n) = *(const f32x4*)(bv + n);
  } else if (blk < NB0 + NB1 + NB2 + NB3) {
    const int b3 = blk - (NB0 + NB1 + NB2);
    const int z = b3 >> 10, rem = b3 & 1023;
    const int by = (rem >> 5) * 32, bx = (rem & 31) * 32;
    const float* W; __bf16* Wt;
    switch (z) {
      case 0: W = Wv;  Wt = d0; break;
      case 1: W = Wo;  Wt = d1; break;
      case 2: W = Wkm; Wt = d2; break;
      case 3: W = Wqm; Wt = d3; break;
      case 4: W = Wk;  Wt = d4; break;
      default: W = Wq; Wt = d5; break;
    }
    const int tx = t & 31, ty = t >> 5;
    if (z < 4) {   // transpose + convert
      for (int i = ty; i < 32; i += 8) tle[i][tx] = W[(size_t)(by + i) * DIM + bx + tx];
      __syncthreads();
      for (int i = ty; i < 32; i += 8) Wt[(size_t)(bx + i) * DIM + by + tx] = (__bf16)tle[tx][i];
    } else {       // straight convert
      for (int i = ty; i < 32; i += 8)
        Wt[(size_t)(by + i) * DIM + bx + tx] = (__bf16)W[(size_t)(by + i) * DIM + bx + tx];
    }
  } else {
    // 2 blocks: full-K bias combine; sole writer of biasAll[1024+which*1024 .. +1024)
    const int which = blk - (NB0 + NB1 + NB2 + NB3);
    const float* bs = which ? bq : bk;
    const float* W  = which ? Wqm : Wkm;
    const float* ba = which ? bqm : bkm;
    const int n0 = t * 4;
    float s0 = 0.f, s1 = 0.f, s2 = 0.f, s3 = 0.f;
#pragma unroll 4
    for (int k = 0; k < DIM; ++k) {
      const float b = bs[k];
      const f32x4 wv = *(const f32x4*)(W + (size_t)k * DIM + n0);
      s0 += b * wv[0]; s1 += b * wv[1]; s2 += b * wv[2]; s3 += b * wv[3];
    }
    const float m = ms[0];
    float* dst = biasAll + 1024 + which * 1024 + n0;
    dst[0] = (s0 + ba[n0 + 0]) * m;
    dst[1] = (s1 + ba[n0 + 1]) * m;
    dst[2] = (s2 + ba[n0 + 2]) * m;
    dst[3] = (s3 + ba[n0 + 3]) * m;
  }
}

// diagnostic fallback: out = x (absmax ~6.5 signals "workspace too small")
__global__ void copyx_kernel(const float* __restrict__ x, float* __restrict__ out, int n4) {
  int i = blockIdx.x * 256 + threadIdx.x;
  if (i >= n4) return;
  ((f32x4*)out)[i] = ((const f32x4*)x)[i];
}

extern "C" void kernel_launch(void* const* d_in, const int* in_sizes, int n_in,
                              void* d_out, int out_size, void* d_ws, size_t ws_size,
                              hipStream_t stream)
{
  (void)in_sizes; (void)n_in; (void)out_size;
  const float* x     = (const float*)d_in[0];
  const float* basep = (const float*)d_in[1];
  const float* Wk    = (const float*)d_in[2];
  const float* bk    = (const float*)d_in[3];
  const float* Wv    = (const float*)d_in[4];
  const float* bv    = (const float*)d_in[5];
  const float* Wq    = (const float*)d_in[6];
  const float* bq    = (const float*)d_in[7];
  const float* Wkm   = (const float*)d_in[8];
  const float* bkm   = (const float*)d_in[9];
  const float* Wqm   = (const float*)d_in[10];
  const float* bqm   = (const float*)d_in[11];
  const float* msc   = (const float*)d_in[12];
  const float* lng   = (const float*)d_in[13];
  const float* lnb   = (const float*)d_in[14];
  const float* Wo    = (const float*)d_in[15];
  const float* bo    = (const float*)d_in[16];

  char* ws = (char*)d_ws;
  const size_t MB = 1ull << 20;
  if (ws_size < 153 * MB) {
    copyx_kernel<<<MROWS * DIM / 4 / 256, 256, 0, stream>>>(x, (float*)d_out, MROWS * DIM / 4);
    return;
  }

  // layout (152 MB + 12 KB):
  __bf16* xb     = (__bf16*)ws;              // [0,32)   x bf16 (stays live for residual)
  __bf16* valb   = (__bf16*)(ws +  32 * MB); // [32,64)
  __bf16* kphb   = (__bf16*)(ws +  64 * MB); // [64,96)  mod-only phase; nbuf aliases it
  __bf16* qphb   = (__bf16*)(ws +  96 * MB); // [96,128)
  __bf16* Ball   = (__bf16*)(ws + 128 * MB); // [128,134) rows: WvT | WkmP | WqmP
  __bf16* WoT    = (__bf16*)(ws + 134 * MB); // [134,136)
  __bf16* TWkm   = (__bf16*)(ws + 136 * MB); // [136,138)
  __bf16* BWk    = (__bf16*)(ws + 138 * MB); // [138,140)
  __bf16* TWqm   = (__bf16*)(ws + 140 * MB); // [140,142)
  __bf16* BWq    = (__bf16*)(ws + 142 * MB); // [142,144)
  __bf16* baseb  = (__bf16*)(ws + 144 * MB); // [144,152) wrapped base_phases bf16
  float*  biasAll= (float*)(ws + 152 * MB);  // 12 KB
  __bf16* nbuf   = kphb;   // phasor overwrites kph rows it has finished reading

  // --- preps: 2 dispatches ---
  prep_all<<<NB0 + NB1 + NB2 + NB3 + 2, 256, 0, stream>>>(
      x, xb, basep, baseb, bv, msc, biasAll,
      Wv, Ball, Wo, WoT, Wkm, TWkm, Wqm, TWqm, Wk, BWk, Wq, BWq,
      bk, bkm, bq, bqm);
  gemm_wc<<<dim3(8, 8, 2), 256, 0, stream>>>(
      TWkm, BWk, Ball + (size_t)1024 * DIM, msc,
      TWqm, BWq, Ball + (size_t)2048 * DIM);

  // --- main pipeline: 3 dispatches ---
  gemm3<<<dim3(24, 128), 256, 0, stream>>>(xb, Ball, biasAll, valb, kphb, qphb);
  phasor_ln<<<NCHUNKBLKS, 256, 0, stream>>>(valb, kphb, qphb, baseb, lng, lnb, nbuf);
  gemm_fin<<<dim3(8, 128), 256, 0, stream>>>(nbuf, WoT, bo, (float*)d_out, xb);
}

// Round 15
// 245.947 us; speedup vs baseline: 1.3402x; 1.3402x over previous
//
#include <hip/hip_runtime.h>

#define DIM 1024
#define SEQ 4096
#define MROWS 16384      // BATCH * SEQ
#define CHUNK 64
#define NCHUNKBLKS 256   // MROWS / CHUNK

typedef float  f32x4  __attribute__((ext_vector_type(4)));
typedef __bf16 bf16x8 __attribute__((ext_vector_type(8)));
typedef __bf16 bf16x4 __attribute__((ext_vector_type(4)));

// async global->LDS, 16B per lane. LDS dest is wave-uniform base + lane*16.
__device__ __forceinline__ void gld16(const void* g, void* l) {
  __builtin_amdgcn_global_load_lds((__attribute__((address_space(1))) void*)g,
                                   (__attribute__((address_space(3))) void*)l,
                                   16, 0, 0);
}

__device__ __forceinline__ f32x4 ld4f(const __bf16* p) {
  bf16x4 v = *(const bf16x4*)p;
  f32x4 r;
#pragma unroll
  for (int j = 0; j < 4; ++j) r[j] = (float)v[j];
  return r;
}

// BK=64 K-loop, single-buffer (proven best structure on this problem).
// T2 both-sides XOR swizzle -> 0 bank conflicts (verified).
#define KLOOP64(As_, Bs_, Ag_, Bg_, AsL_, BsL_)                                  \
  for (int kt = 0; kt < DIM / 64; ++kt) {                                        \
    const __bf16* a_ = Ag_ + kt * 64;                                            \
    const __bf16* b_ = Bg_ + kt * 64;                                            \
    _Pragma("unroll") for (int i = 0; i < 4; ++i) {                              \
      gld16(a_ + i * 32 * DIM, AsL_ + i * 4096);                                 \
      gld16(b_ + i * 32 * DIM, BsL_ + i * 4096);                                 \
    }                                                                            \
    __syncthreads();                                                             \
    const bf16x8* Av_ = (const bf16x8*)(As_);                                    \
    const bf16x8* Bv_ = (const bf16x8*)(Bs_);                                    \
    _Pragma("unroll") for (int kk = 0; kk < 2; ++kk) {                           \
      bf16x8 af[4], bfv[4];                                                      \
      const int pc = (kk * 4 + kg) ^ (lane & 7);                                 \
      _Pragma("unroll") for (int i = 0; i < 4; ++i) af[i]  = Av_[(ar + i*16)*8 + pc]; \
      _Pragma("unroll") for (int i = 0; i < 4; ++i) bfv[i] = Bv_[(br + i*16)*8 + pc]; \
      _Pragma("unroll") for (int mi = 0; mi < 4; ++mi)                           \
        _Pragma("unroll") for (int ni = 0; ni < 4; ++ni)                         \
          acc[mi][ni] = __builtin_amdgcn_mfma_f32_16x16x32_bf16(af[mi], bfv[ni], acc[mi][ni], 0, 0, 0); \
    }                                                                            \
    __syncthreads();                                                             \
  }

// Common per-thread geometry (4 waves, 128x128 tile, BK=64, 128B LDS rows).
#define GEMM_PROLOG64(A_, B_)                                                    \
  const int tid  = threadIdx.x;                                                  \
  const int lane = tid & 63;                                                     \
  const int widx = tid >> 6;                                                     \
  const int wr   = widx >> 1, wc = widx & 1;                                     \
  const int kc = ((lane & 7) ^ ((lane >> 3) & 7)) * 8;                           \
  const __bf16* Ag = (A_) + (size_t)(row0 + widx * 8 + (lane >> 3)) * DIM + kc;  \
  const __bf16* Bg = (B_) + (size_t)(col0 + widx * 8 + (lane >> 3)) * DIM + kc;  \
  char* AsL = (char*)As + widx * 1024;                                           \
  char* BsL = (char*)Bs + widx * 1024;                                           \
  f32x4 acc[4][4] = {};                                                          \
  const int ar = wr * 64 + (lane & 15);                                          \
  const int br = wc * 64 + (lane & 15);                                          \
  const int kg = lane >> 4;

// Final residual GEMM: out f32 = acc + bias + (float)xres_bf16.
// XCD row-band remap, grid (8,128).
__global__ __launch_bounds__(256, 2)
void gemm_fin(const __bf16* __restrict__ A, const __bf16* __restrict__ Bt,
              const float* __restrict__ bias, float* __restrict__ of,
              const __bf16* __restrict__ xres)
{
  __shared__ __bf16 As[128 * 64];   // 16 KB
  __shared__ __bf16 Bs[128 * 64];
  const int b = blockIdx.y * 8 + blockIdx.x;   // grid (8,128)
  const int xcd = b & 7, slot = b >> 3;
  const int col_t = slot & 7;
  const int row_t = (xcd << 4) | (slot >> 3);
  const int row0 = row_t * 128, col0 = col_t * 128;

  GEMM_PROLOG64(A, Bt)
  KLOOP64(As, Bs, Ag, Bg, AsL, BsL)

  // C/D frag mapping (HW-verified): col = lane&15, row = (lane>>4)*4 + r
  const int ccol = col0 + wc * 64 + (lane & 15);
  const int crow = row0 + wr * 64 + kg * 4;
  float bvv[4];
#pragma unroll
  for (int ni = 0; ni < 4; ++ni) bvv[ni] = bias[ccol + ni * 16];
#pragma unroll
  for (int mi = 0; mi < 4; ++mi)
#pragma unroll
    for (int ni = 0; ni < 4; ++ni)
#pragma unroll
      for (int r = 0; r < 4; ++r) {
        const int row = crow + mi * 16 + r;
        const size_t idx = (size_t)row * DIM + ccol + ni * 16;
        of[idx] = acc[mi][ni][r] + bvv[ni] + (float)xres[idx];
      }
}

// Weight-combine GEMM (1024^3 x2): out bf16 = acc * ms.
__global__ __launch_bounds__(256, 2)
void gemm_wc(const __bf16* __restrict__ A, const __bf16* __restrict__ Bt,
             void* __restrict__ outp, const float* __restrict__ mscp,
             const __bf16* __restrict__ A2, const __bf16* __restrict__ Bt2,
             void* __restrict__ out2)
{
  __shared__ __bf16 As[128 * 64];
  __shared__ __bf16 Bs[128 * 64];
  if (blockIdx.z == 1) { A = A2; Bt = Bt2; outp = out2; }
  const int row0 = blockIdx.y * 128, col0 = blockIdx.x * 128;

  GEMM_PROLOG64(A, Bt)
  KLOOP64(As, Bs, Ag, Bg, AsL, BsL)

  const int ccol = col0 + wc * 64 + (lane & 15);
  const int crow = row0 + wr * 64 + kg * 4;
  const float ms = mscp[0];
#pragma unroll
  for (int mi = 0; mi < 4; ++mi)
#pragma unroll
    for (int ni = 0; ni < 4; ++ni)
#pragma unroll
      for (int r = 0; r < 4; ++r) {
        const int row = crow + mi * 16 + r;
        const int col = ccol + ni * 16;
        ((__bf16*)outp)[(size_t)row * DIM + col] = (__bf16)(acc[mi][ni][r] * ms);
      }
}

// Fused x-GEMM (PROVEN 103.5 us structure): C[16384,3072] = xb @ Ball^T,
// Ball rows = [WvT | WkmP | WqmP]. out = bf16(acc + bias); base add + wrap
// deferred to phasor. Grid (24,128). XCD band swizzle, ROW-fastest within XCD.
__global__ __launch_bounds__(256, 2)
void gemm3(const __bf16* __restrict__ A, const __bf16* __restrict__ Ball,
           const float* __restrict__ biasAll,
           __bf16* __restrict__ valb, __bf16* __restrict__ kphb,
           __bf16* __restrict__ qphb)
{
  __shared__ __bf16 As[128 * 64];
  __shared__ __bf16 Bs[128 * 64];
  const int b = blockIdx.y * 24 + blockIdx.x;   // linear id, grid (24,128)
  const int xcd = b & 7, p = b >> 3;            // p in [0,384), bijective
  const int col_t = p / 16;                     // col changes slowest
  const int row_t = (xcd << 4) + (p & 15);      // row-fastest within XCD band
  const int row0 = row_t * 128, col0 = col_t * 128;

  GEMM_PROLOG64(A, Ball)
  KLOOP64(As, Bs, Ag, Bg, AsL, BsL)

  const int band = col_t >> 3;                  // 0:V 1:kph 2:qph
  const int ccol = col0 + wc * 64 + (lane & 15);
  const int lcol0 = ccol & 1023;                // col within the 1024-band
  const int crow = row0 + wr * 64 + kg * 4;
  float bvv[4];
#pragma unroll
  for (int ni = 0; ni < 4; ++ni) bvv[ni] = biasAll[ccol + ni * 16];
  __bf16* outb = (band == 0) ? valb : (band == 1) ? kphb : qphb;
#pragma unroll
  for (int mi = 0; mi < 4; ++mi)
#pragma unroll
    for (int ni = 0; ni < 4; ++ni)
#pragma unroll
      for (int r = 0; r < 4; ++r) {
        const int row = crow + mi * 16 + r;
        const size_t idx = (size_t)row * DIM + lcol0 + ni * 16;
        outb[idx] = (__bf16)(acc[mi][ni][r] + bvv[ni]);
      }
}

// Per chunk (64 rows) x full D: phase = baseb[row&4095] + mod (both bf16);
// in-register cumsum of value*e^{i*kph}, retrieve with qph, /sqrt(D),
// per-row LayerNorm, emit bf16 normed. 8-row batches for shfl-chain ILP.
// (Round-11 proven version.) nb ALIASES kph (nbuf = kphb): batch reads
// complete before writes to those rows; kph/nb deliberately NOT __restrict__.
__global__ __launch_bounds__(256)
void phasor_ln(const __bf16* __restrict__ val, const __bf16* kph,
               const __bf16* __restrict__ qph, const __bf16* __restrict__ baseb,
               const float* __restrict__ g, const float* __restrict__ lb,
               __bf16* nb)
{
  const int t = threadIdx.x;
  const int w = t >> 6, lane = t & 63;
  const size_t r0 = (size_t)blockIdx.x * CHUNK;
  const int c = t * 4;
  const f32x4 gv  = ((const f32x4*)g)[t];
  const f32x4 lbv = ((const f32x4*)lb)[t];
  __shared__ float redS[8][4], redQ[8][4];
  float mr[4] = {0.f, 0.f, 0.f, 0.f};
  float mi[4] = {0.f, 0.f, 0.f, 0.f};
  for (int rb = 0; rb < 8; ++rb) {
    float ret[8][4], ss[8], qq[8];
#pragma unroll
    for (int r = 0; r < 8; ++r) {
      const int row = rb * 8 + r;
      const size_t base = (r0 + row) * DIM + c;
      const f32x4 v  = ld4f(val + base);
      const f32x4 kp = ld4f(kph + base);
      const f32x4 qp = ld4f(qph + base);
      const f32x4 bp = ld4f(baseb + (size_t)((r0 + row) & (SEQ - 1)) * DIM + c);
      float s = 0.f, q = 0.f;
#pragma unroll
      for (int j = 0; j < 4; ++j) {
        float sk, ck, sq, cq;
        __sincosf(bp[j] + kp[j], &sk, &ck);
        mr[j] += v[j] * ck;
        mi[j] += v[j] * sk;
        __sincosf(bp[j] + qp[j], &sq, &cq);
        ret[r][j] = (mr[j] * cq + mi[j] * sq) * 0.03125f;   // 1/sqrt(1024)
        s += ret[r][j];
        q += ret[r][j] * ret[r][j];
      }
      ss[r] = s; qq[r] = q;
    }
#pragma unroll
    for (int off = 32; off > 0; off >>= 1)
#pragma unroll
      for (int r = 0; r < 8; ++r) {
        ss[r] += __shfl_down(ss[r], off);
        qq[r] += __shfl_down(qq[r], off);
      }
    if (lane == 0)
#pragma unroll
      for (int r = 0; r < 8; ++r) { redS[r][w] = ss[r]; redQ[r][w] = qq[r]; }
    __syncthreads();
#pragma unroll
    for (int r = 0; r < 8; ++r) {
      const float mu   = (redS[r][0] + redS[r][1] + redS[r][2] + redS[r][3]) * (1.0f / DIM);
      const float varr = (redQ[r][0] + redQ[r][1] + redQ[r][2] + redQ[r][3]) * (1.0f / DIM) - mu * mu;
      const float rinv = rsqrtf(varr + 1e-5f);
      bf16x4 o;
#pragma unroll
      for (int j = 0; j < 4; ++j) o[j] = (__bf16)((ret[r][j] - mu) * rinv * gv[j] + lbv[j]);
      *(bf16x4*)(nb + (r0 + rb * 8 + r) * DIM + c) = o;
    }
    __syncthreads();
  }
}

// ---------------------------------------------------------------------------
// Merged parallel prep (block-segmented; ALL segments are data-parallel —
// the serial full-K bias combine is back in its own k-split dispatch, whose
// 2-block serial version cost 100+ us as a lone tail in round 14):
//  seg0: f2b x->xb                       (16384 blocks)
//  seg1: wrap+bf16 basep->baseb          ( 4096 blocks)
//  seg2: biasinit (bv | bkm*ms | bqm*ms) (    1 block )
//  seg3: 6 weight transposes/converts    ( 6144 blocks)
// ---------------------------------------------------------------------------
#define NB0 16384
#define NB1 4096
#define NB2 1
#define NB3 6144
__global__ void prep_all(const float* __restrict__ x, __bf16* __restrict__ xb,
                         const float* __restrict__ basep, __bf16* __restrict__ baseb,
                         const float* __restrict__ bv, const float* __restrict__ ms,
                         float* __restrict__ biasAll,
                         const float* __restrict__ Wv, __bf16* __restrict__ d0,
                         const float* __restrict__ Wo, __bf16* __restrict__ d1,
                         const float* __restrict__ Wkm, __bf16* __restrict__ d2,
                         const float* __restrict__ Wqm, __bf16* __restrict__ d3,
                         const float* __restrict__ Wk, __bf16* __restrict__ d4,
                         const float* __restrict__ Wq, __bf16* __restrict__ d5,
                         const float* __restrict__ bkm, const float* __restrict__ bqm)
{
  __shared__ float tle[32][33];
  const int blk = blockIdx.x;
  const int t = threadIdx.x;
  if (blk < NB0) {
    const int i = blk * 256 + t;
    f32x4 vv = ((const f32x4*)x)[i];
    bf16x4 o;
#pragma unroll
    for (int j = 0; j < 4; ++j) o[j] = (__bf16)vv[j];
    ((bf16x4*)xb)[i] = o;
  } else if (blk < NB0 + NB1) {
    const int i = (blk - NB0) * 256 + t;
    f32x4 vv = ((const f32x4*)basep)[i];
    bf16x4 o;
#pragma unroll
    for (int j = 0; j < 4; ++j) {
      float v = vv[j];
      v -= 6.2831853f * rintf(v * 0.15915494f);
      o[j] = (__bf16)v;
    }
    ((bf16x4*)baseb)[i] = o;
  } else if (blk < NB0 + NB1 + NB2) {
    // 1 block: biasAll init (biasacc atomically accumulates on top, next dispatch)
    const int n = t * 4;
    const float m = ms[0];
    *(f32x4*)(biasAll + n) = *(const f32x4*)(bv + n);
    f32x4 a = *(const f32x4*)(bkm + n);
    f32x4 b = *(const f32x4*)(bqm + n);
#pragma unroll
    for (int j = 0; j < 4; ++j) { a[j] *= m; b[j] *= m; }
    *(f32x4*)(biasAll + 1024 + n) = a;
    *(f32x4*)(biasAll + 2048 + n) = b;
  } else {
    const int b3 = blk - (NB0 + NB1 + NB2);
    const int z = b3 >> 10, rem = b3 & 1023;
    const int by = (rem >> 5) * 32, bx = (rem & 31) * 32;
    const float* W; __bf16* Wt;
    switch (z) {
      case 0: W = Wv;  Wt = d0; break;
      case 1: W = Wo;  Wt = d1; break;
      case 2: W = Wkm; Wt = d2; break;
      case 3: W = Wqm; Wt = d3; break;
      case 4: W = Wk;  Wt = d4; break;
      default: W = Wq; Wt = d5; break;
    }
    const int tx = t & 31, ty = t >> 5;
    if (z < 4) {   // transpose + convert
      for (int i = ty; i < 32; i += 8) tle[i][tx] = W[(size_t)(by + i) * DIM + bx + tx];
      __syncthreads();
      for (int i = ty; i < 32; i += 8) Wt[(size_t)(bx + i) * DIM + by + tx] = (__bf16)tle[tx][i];
    } else {       // straight convert
      for (int i = ty; i < 32; i += 8)
        Wt[(size_t)(by + i) * DIM + bx + tx] = (__bf16)W[(size_t)(by + i) * DIM + bx + tx];
    }
  }
}

// k-parallel bias combine: biasAll[1024+which*1024+n] += ms * sum_k bs[k]*W[k][n]
// grid (1,2,8): 128-k segments, atomic accumulate (init done by prep_all seg2).
__global__ void biasacc(const float* __restrict__ bk, const float* __restrict__ Wkm,
                        const float* __restrict__ bq, const float* __restrict__ Wqm,
                        const float* __restrict__ ms, float* __restrict__ biasAll) {
  const int t = threadIdx.x;
  const int which = blockIdx.y;
  const int k0 = blockIdx.z * 128;
  const float* bs = which ? bq : bk;
  const float* W  = which ? Wqm : Wkm;
  const int n0 = t * 4;
  float s0 = 0.f, s1 = 0.f, s2 = 0.f, s3 = 0.f;
  for (int k = k0; k < k0 + 128; ++k) {
    const float b = bs[k];
    const f32x4 wv = *(const f32x4*)(W + (size_t)k * DIM + n0);
    s0 += b * wv[0]; s1 += b * wv[1]; s2 += b * wv[2]; s3 += b * wv[3];
  }
  const float m = ms[0];
  float* dst = biasAll + 1024 + which * 1024 + n0;
  atomicAdd(dst + 0, s0 * m);
  atomicAdd(dst + 1, s1 * m);
  atomicAdd(dst + 2, s2 * m);
  atomicAdd(dst + 3, s3 * m);
}

// diagnostic fallback: out = x (absmax ~6.5 signals "workspace too small")
__global__ void copyx_kernel(const float* __restrict__ x, float* __restrict__ out, int n4) {
  int i = blockIdx.x * 256 + threadIdx.x;
  if (i >= n4) return;
  ((f32x4*)out)[i] = ((const f32x4*)x)[i];
}

extern "C" void kernel_launch(void* const* d_in, const int* in_sizes, int n_in,
                              void* d_out, int out_size, void* d_ws, size_t ws_size,
                              hipStream_t stream)
{
  (void)in_sizes; (void)n_in; (void)out_size;
  const float* x     = (const float*)d_in[0];
  const float* basep = (const float*)d_in[1];
  const float* Wk    = (const float*)d_in[2];
  const float* bk    = (const float*)d_in[3];
  const float* Wv    = (const float*)d_in[4];
  const float* bv    = (const float*)d_in[5];
  const float* Wq    = (const float*)d_in[6];
  const float* bq    = (const float*)d_in[7];
  const float* Wkm   = (const float*)d_in[8];
  const float* bkm   = (const float*)d_in[9];
  const float* Wqm   = (const float*)d_in[10];
  const float* bqm   = (const float*)d_in[11];
  const float* msc   = (const float*)d_in[12];
  const float* lng   = (const float*)d_in[13];
  const float* lnb   = (const float*)d_in[14];
  const float* Wo    = (const float*)d_in[15];
  const float* bo    = (const float*)d_in[16];

  char* ws = (char*)d_ws;
  const size_t MB = 1ull << 20;
  if (ws_size < 153 * MB) {
    copyx_kernel<<<MROWS * DIM / 4 / 256, 256, 0, stream>>>(x, (float*)d_out, MROWS * DIM / 4);
    return;
  }

  // layout (152 MB + 12 KB):
  __bf16* xb     = (__bf16*)ws;              // [0,32)   x bf16 (stays live for residual)
  __bf16* valb   = (__bf16*)(ws +  32 * MB); // [32,64)
  __bf16* kphb   = (__bf16*)(ws +  64 * MB); // [64,96)  mod-only phase; nbuf aliases it
  __bf16* qphb   = (__bf16*)(ws +  96 * MB); // [96,128)
  __bf16* Ball   = (__bf16*)(ws + 128 * MB); // [128,134) rows: WvT | WkmP | WqmP
  __bf16* WoT    = (__bf16*)(ws + 134 * MB); // [134,136)
  __bf16* TWkm   = (__bf16*)(ws + 136 * MB); // [136,138)
  __bf16* BWk    = (__bf16*)(ws + 138 * MB); // [138,140)
  __bf16* TWqm   = (__bf16*)(ws + 140 * MB); // [140,142)
  __bf16* BWq    = (__bf16*)(ws + 142 * MB); // [142,144)
  __bf16* baseb  = (__bf16*)(ws + 144 * MB); // [144,152) wrapped base_phases bf16
  float*  biasAll= (float*)(ws + 152 * MB);  // 12 KB
  __bf16* nbuf   = kphb;   // phasor overwrites kph rows it has finished reading

  // --- preps: 3 dispatches ---
  prep_all<<<NB0 + NB1 + NB2 + NB3, 256, 0, stream>>>(
      x, xb, basep, baseb, bv, msc, biasAll,
      Wv, Ball, Wo, WoT, Wkm, TWkm, Wqm, TWqm, Wk, BWk, Wq, BWq,
      bkm, bqm);
  biasacc<<<dim3(1, 2, 8), 256, 0, stream>>>(bk, Wkm, bq, Wqm, msc, biasAll);
  gemm_wc<<<dim3(8, 8, 2), 256, 0, stream>>>(
      TWkm, BWk, Ball + (size_t)1024 * DIM, msc,
      TWqm, BWq, Ball + (size_t)2048 * DIM);

  // --- main pipeline: 3 dispatches ---
  gemm3<<<dim3(24, 128), 256, 0, stream>>>(xb, Ball, biasAll, valb, kphb, qphb);
  phasor_ln<<<NCHUNKBLKS, 256, 0, stream>>>(valb, kphb, qphb, baseb, lng, lnb, nbuf);
  gemm_fin<<<dim3(8, 128), 256, 0, stream>>>(nbuf, WoT, bo, (float*)d_out, xb);
}